// Round 1
// baseline (221.971 us; speedup 1.0000x reference)
//
#include <hip/hip_runtime.h>
#include <cmath>

// Pipeline:
//  seg[a]     = lower_bound(assign, a)              (assign is sorted)
//  anchor[b,a,:] = sum_{t in seg} x[b,t,:] / counts[a]
//  M          = W_graph ^ hops                      (hops read on device)
//  agg[b,a,:] = sum_c M[a,c] * anchor[b,c,:]
//  Y[b,a,:]   = agg[b,a,:] @ W_proj^T               (only B*A=256 distinct fb rows!)
//  out[b,t,:] = x[b,t,:] + tanh(gate) * Y[b,assign[t],:]

__global__ void seg_kernel(const int* __restrict__ assign, int T, int A,
                           int* __restrict__ seg) {
    int a = blockIdx.x * blockDim.x + threadIdx.x;
    if (a > A) return;
    int lo = 0, hi = T;
    while (lo < hi) { int mid = (lo + hi) >> 1; if (assign[mid] < a) lo = mid + 1; else hi = mid; }
    seg[a] = lo;
}

// grid = B*A blocks, 256 threads; each block reduces one (b,a) segment.
__global__ void anchor_kernel(const float* __restrict__ x, const float* __restrict__ counts,
                              const int* __restrict__ seg, float* __restrict__ anchor,
                              int T, int D, int A) {
    int b = blockIdx.x / A, a = blockIdx.x % A;
    int t0 = seg[a], t1 = seg[a + 1];
    float inv = 1.0f / counts[a];
    int rowStride = D >> 2;                       // float4 per row
    const float4* x4 = (const float4*)x;
    float4* an4 = (float4*)anchor;
    for (int d4 = threadIdx.x; d4 < rowStride; d4 += blockDim.x) {
        float4 acc = make_float4(0.f, 0.f, 0.f, 0.f);
        const float4* p = x4 + ((size_t)b * T + t0) * rowStride + d4;
        for (int t = t0; t < t1; ++t, p += rowStride) {
            float4 v = *p;
            acc.x += v.x; acc.y += v.y; acc.z += v.z; acc.w += v.w;
        }
        acc.x *= inv; acc.y *= inv; acc.z *= inv; acc.w *= inv;
        an4[(size_t)blockIdx.x * rowStride + d4] = acc;
    }
}

// 1 block; computes M = W^h entirely in LDS (A <= 64).
__global__ void mpow_kernel(const float* __restrict__ W, const int* __restrict__ hops,
                            float* __restrict__ M, int A) {
    __shared__ float cur[64 * 64];
    __shared__ float nxt[64 * 64];
    int n = A * A;
    for (int i = threadIdx.x; i < n; i += blockDim.x) cur[i] = W[i];
    int h = hops[0]; if (h < 1) h = 1;
    for (int it = 1; it < h; ++it) {
        __syncthreads();
        for (int i = threadIdx.x; i < n; i += blockDim.x) {
            int r = i / A, c = i % A;
            float s = 0.f;
            for (int k = 0; k < A; ++k) s += W[r * A + k] * cur[k * A + c];
            nxt[i] = s;
        }
        __syncthreads();
        for (int i = threadIdx.x; i < n; i += blockDim.x) cur[i] = nxt[i];
    }
    __syncthreads();
    for (int i = threadIdx.x; i < n; i += blockDim.x) M[i] = cur[i];
}

// grid = B*A blocks; agg[b,a,:] = sum_c M[a,c] * anchor[b,c,:]
__global__ void agg_kernel(const float* __restrict__ anchor, const float* __restrict__ M,
                           float* __restrict__ agg, int D, int A) {
    int b = blockIdx.x / A, a = blockIdx.x % A;
    __shared__ float row[64];
    if (threadIdx.x < A) row[threadIdx.x] = M[a * A + threadIdx.x];
    __syncthreads();
    int rowStride = D >> 2;
    const float4* an4 = (const float4*)anchor;
    float4* ag4 = (float4*)agg;
    for (int d4 = threadIdx.x; d4 < rowStride; d4 += blockDim.x) {
        float4 acc = make_float4(0.f, 0.f, 0.f, 0.f);
        for (int c = 0; c < A; ++c) {
            float w = row[c];
            float4 v = an4[((size_t)b * A + c) * rowStride + d4];
            acc.x += w * v.x; acc.y += w * v.y; acc.z += w * v.z; acc.w += w * v.w;
        }
        ag4[(size_t)blockIdx.x * rowStride + d4] = acc;
    }
}

// Y[r,d] = sum_k Ag[r,k] * Wp[d,k]   (r = b*A+a; both operands contiguous in k)
#define TM 32
#define TN 128
#define KT 32
__global__ void ygemm_kernel(const float* __restrict__ Ag, const float* __restrict__ Wp,
                             float* __restrict__ Y, int R, int D) {
    __shared__ float As[TM][KT + 1];
    __shared__ float Bs[TN][KT + 1];
    int rBase = blockIdx.x * TM;
    int cBase = blockIdx.y * TN;
    int tid = threadIdx.x;
    int tr = tid >> 5;       // 0..7   -> 4 rows each
    int tc = tid & 31;       // 0..31  -> 4 cols each
    float acc[4][4] = {};
    for (int k0 = 0; k0 < D; k0 += KT) {
        for (int i = tid; i < TM * KT; i += 256) {
            int r = i / KT, k = i % KT;
            As[r][k] = Ag[(size_t)(rBase + r) * D + k0 + k];
        }
        for (int i = tid; i < TN * KT; i += 256) {
            int d = i / KT, k = i % KT;
            Bs[d][k] = Wp[(size_t)(cBase + d) * D + k0 + k];
        }
        __syncthreads();
        #pragma unroll
        for (int k = 0; k < KT; ++k) {
            float ar[4], br[4];
            #pragma unroll
            for (int i = 0; i < 4; ++i) ar[i] = As[tr * 4 + i][k];
            #pragma unroll
            for (int j = 0; j < 4; ++j) br[j] = Bs[tc * 4 + j][k];
            #pragma unroll
            for (int i = 0; i < 4; ++i)
                #pragma unroll
                for (int j = 0; j < 4; ++j)
                    acc[i][j] += ar[i] * br[j];
        }
        __syncthreads();
    }
    for (int i = 0; i < 4; ++i)
        for (int j = 0; j < 4; ++j)
            Y[(size_t)(rBase + tr * 4 + i) * D + cBase + tc * 4 + j] = acc[i][j];
}

// grid = B*T blocks, 256 threads; out row = x row + tg * Y[gathered row]
__global__ void out_kernel(const float* __restrict__ x, const float* __restrict__ Y,
                           const int* __restrict__ assign, const float* __restrict__ gate,
                           float* __restrict__ out, int T, int D, int A) {
    int bt = blockIdx.x;
    int t = bt % T;
    int b = bt / T;
    int a = assign[t];
    float tg = tanhf(gate[0]);
    int rowStride = D >> 2;
    const float4* x4 = (const float4*)x + (size_t)bt * rowStride;
    const float4* y4 = (const float4*)Y + ((size_t)b * A + a) * rowStride;
    float4* o4 = (float4*)out + (size_t)bt * rowStride;
    for (int d4 = threadIdx.x; d4 < rowStride; d4 += blockDim.x) {
        float4 xv = x4[d4];
        float4 yv = y4[d4];
        o4[d4] = make_float4(xv.x + tg * yv.x, xv.y + tg * yv.y,
                             xv.z + tg * yv.z, xv.w + tg * yv.w);
    }
}

extern "C" void kernel_launch(void* const* d_in, const int* in_sizes, int n_in,
                              void* d_out, int out_size, void* d_ws, size_t ws_size,
                              hipStream_t stream) {
    const float* x      = (const float*)d_in[0];
    const float* Wp     = (const float*)d_in[1];
    const float* gate   = (const float*)d_in[2];
    const int*   assign = (const int*)d_in[3];
    const float* Wg     = (const float*)d_in[4];
    const float* counts = (const float*)d_in[5];
    const int*   hops   = (const int*)d_in[6];
    float* out = (float*)d_out;

    int T = in_sizes[3];
    int A = in_sizes[5];
    int D = (int)(sqrt((double)in_sizes[1]) + 0.5);
    int B = (int)(in_sizes[0] / ((long long)T * D));
    int R = B * A;

    // workspace layout (floats)
    float* anchor = (float*)d_ws;
    float* agg    = anchor + (size_t)R * D;
    float* Y      = agg    + (size_t)R * D;
    float* M      = Y      + (size_t)R * D;
    int*   seg    = (int*)(M + (size_t)A * A);

    seg_kernel<<<1, 128, 0, stream>>>(assign, T, A, seg);
    anchor_kernel<<<R, 256, 0, stream>>>(x, counts, seg, anchor, T, D, A);
    mpow_kernel<<<1, 256, 0, stream>>>(Wg, hops, M, A);
    agg_kernel<<<R, 256, 0, stream>>>(anchor, M, agg, D, A);
    dim3 g(R / TM, D / TN);
    ygemm_kernel<<<g, 256, 0, stream>>>(agg, Wp, Y, R, D);
    out_kernel<<<B * T, 256, 0, stream>>>(x, Y, assign, gate, out, T, D, A);
}

// Round 2
// 100.879 us; speedup vs baseline: 2.2004x; 2.2004x over previous
//
#include <hip/hip_runtime.h>
#include <cmath>

// Pipeline:
//  seg[a]        = lower_bound(assign, a)              (assign is sorted)
//  anchor[b,a,:] = sum_{t in seg} x[b,t,:] / counts[a]
//  M             = W_graph ^ hops                      (hops read on device)
//  agg[b,a,:]    = sum_c M[a,c] * anchor[b,c,:]
//  Yp[s]         = partial (agg @ W_proj^T) over K-slice s   (split-K GEMM)
//  Y             = sum_s Yp[s]
//  out[b,t,:]    = x[b,t,:] + tanh(gate) * Y[b,assign[t],:]

__global__ void seg_kernel(const int* __restrict__ assign, int T, int A,
                           int* __restrict__ seg) {
    int a = blockIdx.x * blockDim.x + threadIdx.x;
    if (a > A) return;
    int lo = 0, hi = T;
    while (lo < hi) { int mid = (lo + hi) >> 1; if (assign[mid] < a) lo = mid + 1; else hi = mid; }
    seg[a] = lo;
}

// grid = B*A blocks, 256 threads; each block reduces one (b,a) segment.
// t-loop unrolled x4 for 4 outstanding HBM loads.
__global__ void anchor_kernel(const float* __restrict__ x, const float* __restrict__ counts,
                              const int* __restrict__ seg, float* __restrict__ anchor,
                              int T, int D, int A) {
    int b = blockIdx.x / A, a = blockIdx.x % A;
    int t0 = seg[a], t1 = seg[a + 1];
    float inv = 1.0f / counts[a];
    int rs = D >> 2;
    const float4* x4 = (const float4*)x + (size_t)b * T * rs;
    float4* an4 = (float4*)anchor + (size_t)blockIdx.x * rs;
    for (int d4 = threadIdx.x; d4 < rs; d4 += blockDim.x) {
        float4 acc = make_float4(0.f, 0.f, 0.f, 0.f);
        const float4* p = x4 + (size_t)t0 * rs + d4;
        int t = t0;
        for (; t + 4 <= t1; t += 4) {
            float4 v0 = p[0];
            float4 v1 = p[(size_t)rs];
            float4 v2 = p[(size_t)2 * rs];
            float4 v3 = p[(size_t)3 * rs];
            acc.x += (v0.x + v1.x) + (v2.x + v3.x);
            acc.y += (v0.y + v1.y) + (v2.y + v3.y);
            acc.z += (v0.z + v1.z) + (v2.z + v3.z);
            acc.w += (v0.w + v1.w) + (v2.w + v3.w);
            p += (size_t)4 * rs;
        }
        for (; t < t1; ++t) {
            float4 v = *p;
            acc.x += v.x; acc.y += v.y; acc.z += v.z; acc.w += v.w;
            p += rs;
        }
        an4[d4] = make_float4(acc.x * inv, acc.y * inv, acc.z * inv, acc.w * inv);
    }
}

// 1 block; computes M = W^h entirely in LDS (A <= 64).
__global__ void mpow_kernel(const float* __restrict__ W, const int* __restrict__ hops,
                            float* __restrict__ M, int A) {
    __shared__ float cur[64 * 64];
    __shared__ float nxt[64 * 64];
    int n = A * A;
    for (int i = threadIdx.x; i < n; i += blockDim.x) cur[i] = W[i];
    int h = hops[0]; if (h < 1) h = 1;
    for (int it = 1; it < h; ++it) {
        __syncthreads();
        for (int i = threadIdx.x; i < n; i += blockDim.x) {
            int r = i / A, c = i % A;
            float s = 0.f;
            for (int k = 0; k < A; ++k) s += W[r * A + k] * cur[k * A + c];
            nxt[i] = s;
        }
        __syncthreads();
        for (int i = threadIdx.x; i < n; i += blockDim.x) cur[i] = nxt[i];
    }
    __syncthreads();
    for (int i = threadIdx.x; i < n; i += blockDim.x) M[i] = cur[i];
}

// grid = B*A blocks; agg[b,a,:] = sum_c M[a,c] * anchor[b,c,:]
__global__ void agg_kernel(const float* __restrict__ anchor, const float* __restrict__ M,
                           float* __restrict__ agg, int D, int A) {
    int b = blockIdx.x / A, a = blockIdx.x % A;
    __shared__ float row[64];
    if (threadIdx.x < A) row[threadIdx.x] = M[a * A + threadIdx.x];
    __syncthreads();
    int rs = D >> 2;
    const float4* an4 = (const float4*)anchor;
    float4* ag4 = (float4*)agg;
    for (int d4 = threadIdx.x; d4 < rs; d4 += blockDim.x) {
        float4 acc = make_float4(0.f, 0.f, 0.f, 0.f);
        for (int c = 0; c < A; ++c) {
            float w = row[c];
            float4 v = an4[((size_t)b * A + c) * rs + d4];
            acc.x += w * v.x; acc.y += w * v.y; acc.z += w * v.z; acc.w += w * v.w;
        }
        ag4[(size_t)blockIdx.x * rs + d4] = acc;
    }
}

// Split-K GEMM: Yp[z][r][d] += Ag[r, kz..kz+kChunk) . Wp[d, kz..kz+kChunk)
// 128x128 tile, 8x8 register tile per thread, transposed LDS (k-major),
// float4 LDS reads, register-prefetch staging pipeline.
#define GTM 128
#define GTN 128
#define GKT 8
#define LDP 132   // LDS row stride in floats: 132*4B = 528B, 16B-aligned, bank-shifted
__global__ void ygemm_kernel(const float* __restrict__ Ag, const float* __restrict__ Wp,
                             float* __restrict__ Yp, int R, int D, int kChunk) {
    __shared__ float As[GKT * LDP];
    __shared__ float Bs[GKT * LDP];
    int rBase = blockIdx.x * GTM;
    int cBase = blockIdx.y * GTN;
    int kBase = blockIdx.z * kChunk;
    int tid = threadIdx.x;
    int tr = tid >> 4;          // 0..15 -> rows tr*8..tr*8+7
    int tc = tid & 15;          // 0..15 -> cols tc*8..tc*8+7
    int sr = tid >> 1;          // staging row 0..127
    int sk = (tid & 1) * 4;     // staging k-offset 0 or 4

    const float* aSrc = Ag + (size_t)(rBase + sr) * D + kBase + sk;
    const float* bSrc = Wp + (size_t)(cBase + sr) * D + kBase + sk;

    float acc[8][8] = {};

    // prologue: prefetch tile 0 into registers
    float4 av = *(const float4*)aSrc;
    float4 bv = *(const float4*)bSrc;

    int nSteps = kChunk / GKT;
    for (int s = 0; s < nSteps; ++s) {
        // write staged regs into transposed LDS
        As[(sk + 0) * LDP + sr] = av.x;
        As[(sk + 1) * LDP + sr] = av.y;
        As[(sk + 2) * LDP + sr] = av.z;
        As[(sk + 3) * LDP + sr] = av.w;
        Bs[(sk + 0) * LDP + sr] = bv.x;
        Bs[(sk + 1) * LDP + sr] = bv.y;
        Bs[(sk + 2) * LDP + sr] = bv.z;
        Bs[(sk + 3) * LDP + sr] = bv.w;
        __syncthreads();
        // prefetch next tile (latency hides under the inner loop)
        if (s + 1 < nSteps) {
            av = *(const float4*)(aSrc + (s + 1) * GKT);
            bv = *(const float4*)(bSrc + (s + 1) * GKT);
        }
        #pragma unroll
        for (int k = 0; k < GKT; ++k) {
            float4 a0 = *(const float4*)&As[k * LDP + tr * 8];
            float4 a1 = *(const float4*)&As[k * LDP + tr * 8 + 4];
            float4 b0 = *(const float4*)&Bs[k * LDP + tc * 8];
            float4 b1 = *(const float4*)&Bs[k * LDP + tc * 8 + 4];
            float ar[8] = {a0.x, a0.y, a0.z, a0.w, a1.x, a1.y, a1.z, a1.w};
            float br[8] = {b0.x, b0.y, b0.z, b0.w, b1.x, b1.y, b1.z, b1.w};
            #pragma unroll
            for (int i = 0; i < 8; ++i)
                #pragma unroll
                for (int j = 0; j < 8; ++j)
                    acc[i][j] += ar[i] * br[j];
        }
        __syncthreads();
    }

    float* yp = Yp + (size_t)blockIdx.z * R * D;
    #pragma unroll
    for (int i = 0; i < 8; ++i) {
        float* row = yp + (size_t)(rBase + tr * 8 + i) * D + cBase + tc * 8;
        *(float4*)row       = make_float4(acc[i][0], acc[i][1], acc[i][2], acc[i][3]);
        *(float4*)(row + 4) = make_float4(acc[i][4], acc[i][5], acc[i][6], acc[i][7]);
    }
}

// Y = sum_s Yp[s]; grid*block == R*D/4 exactly.
__global__ void yred_kernel(const float* __restrict__ Yp, float* __restrict__ Y,
                            long long n4, int S) {
    long long i = (long long)blockIdx.x * blockDim.x + threadIdx.x;
    if (i >= n4) return;
    const float4* p = (const float4*)Yp;
    float4 acc = p[i];
    for (int s = 1; s < S; ++s) {
        float4 v = p[(size_t)s * n4 + i];
        acc.x += v.x; acc.y += v.y; acc.z += v.z; acc.w += v.w;
    }
    ((float4*)Y)[i] = acc;
}

// grid = B*T/ROWS blocks, 256 threads; out row = x row + tg * Y[gathered row]
#define OROWS 4
__global__ void out_kernel(const float* __restrict__ x, const float* __restrict__ Y,
                           const int* __restrict__ assign, const float* __restrict__ gate,
                           float* __restrict__ out, int T, int D, int A) {
    float tg = tanhf(gate[0]);
    int rs = D >> 2;
    int bt0 = blockIdx.x * OROWS;
    const float4* x4 = (const float4*)x;
    const float4* y4 = (const float4*)Y;
    float4* o4 = (float4*)out;
    #pragma unroll
    for (int r = 0; r < OROWS; ++r) {
        int bt = bt0 + r;
        int b = bt / T;
        int t = bt - b * T;
        int a = assign[t];
        const float4* yr = y4 + ((size_t)b * A + a) * rs;
        for (int d4 = threadIdx.x; d4 < rs; d4 += blockDim.x) {
            float4 xv = x4[(size_t)bt * rs + d4];
            float4 yv = yr[d4];
            o4[(size_t)bt * rs + d4] = make_float4(xv.x + tg * yv.x, xv.y + tg * yv.y,
                                                   xv.z + tg * yv.z, xv.w + tg * yv.w);
        }
    }
}

extern "C" void kernel_launch(void* const* d_in, const int* in_sizes, int n_in,
                              void* d_out, int out_size, void* d_ws, size_t ws_size,
                              hipStream_t stream) {
    const float* x      = (const float*)d_in[0];
    const float* Wp     = (const float*)d_in[1];
    const float* gate   = (const float*)d_in[2];
    const int*   assign = (const int*)d_in[3];
    const float* Wg     = (const float*)d_in[4];
    const float* counts = (const float*)d_in[5];
    const int*   hops   = (const int*)d_in[6];
    float* out = (float*)d_out;

    int T = in_sizes[3];
    int A = in_sizes[5];
    int D = (int)(sqrt((double)in_sizes[1]) + 0.5);
    int B = (int)(in_sizes[0] / ((long long)T * D));
    int R = B * A;

    // workspace layout (floats)
    float* anchor = (float*)d_ws;
    float* agg    = anchor + (size_t)R * D;
    float* Y      = agg    + (size_t)R * D;
    float* M      = Y      + (size_t)R * D;
    int*   seg    = (int*)(M + (size_t)A * A);
    float* Yp     = (float*)(seg + 68);          // 16B-aligned (offset divisible by 4 floats)

    size_t baseFloats = (size_t)R * D * 3 + (size_t)A * A + 68;
    size_t sliceFloats = (size_t)R * D;
    long long avail = (long long)(ws_size / 4) - (long long)baseFloats;
    int splitK = 1;
    for (int s = 16; s >= 1; s >>= 1) {
        if ((long long)s * sliceFloats <= avail && (D / s) % GKT == 0) { splitK = s; break; }
    }
    if (splitK == 1) Yp = Y;                      // no partials needed
    int kChunk = D / splitK;

    seg_kernel<<<1, 128, 0, stream>>>(assign, T, A, seg);
    anchor_kernel<<<R, 256, 0, stream>>>(x, counts, seg, anchor, T, D, A);
    mpow_kernel<<<1, 256, 0, stream>>>(Wg, hops, M, A);
    agg_kernel<<<R, 256, 0, stream>>>(anchor, M, agg, D, A);

    dim3 g(R / GTM, D / GTN, splitK);
    ygemm_kernel<<<g, 256, 0, stream>>>(agg, Wp, Yp, R, D, kChunk);
    if (splitK > 1) {
        long long n4 = (long long)R * D / 4;
        int blocks = (int)((n4 + 255) / 256);
        yred_kernel<<<blocks, 256, 0, stream>>>(Yp, Y, n4, splitK);
    }

    out_kernel<<<B * T / OROWS, 256, 0, stream>>>(x, Y, assign, gate, out, T, D, A);
}

// Round 3
// 71.187 us; speedup vs baseline: 3.1181x; 1.4171x over previous
//
#include <hip/hip_runtime.h>
#include <cmath>

// Pipeline:
//  seg[a]        = lower_bound(assign, a)              (assign is sorted)
//  anchor[b,a,:] = sum_{t in seg} x[b,t,:] / counts[a]    (f32)
//  M             = W_graph ^ hops                      (hops read on device)
//  aggb[b,a,:]   = bf16( sum_c M[a,c] * anchor[b,c,:] )
//  Wpb           = bf16(W_proj)
//  Y[r,d]        = mfma bf16 GEMM: aggb[r,:] . Wpb[d,:]   (f32 out, no LDS)
//  out[b,t,:]    = x[b,t,:] + tanh(gate) * Y[b,assign[t],:]

typedef __attribute__((ext_vector_type(8))) short bf16x8;
typedef __attribute__((ext_vector_type(4))) float f32x4;

__device__ inline short f2bf(float f) {            // round-to-nearest-even
    unsigned u = __float_as_uint(f);
    unsigned r = (u + 0x7FFFu + ((u >> 16) & 1u)) >> 16;
    return (short)r;
}

__global__ void seg_kernel(const int* __restrict__ assign, int T, int A,
                           int* __restrict__ seg) {
    int a = blockIdx.x * blockDim.x + threadIdx.x;
    if (a > A) return;
    int lo = 0, hi = T;
    while (lo < hi) { int mid = (lo + hi) >> 1; if (assign[mid] < a) lo = mid + 1; else hi = mid; }
    seg[a] = lo;
}

// grid = B*A blocks, 256 threads; each block reduces one (b,a) segment.
__global__ void anchor_kernel(const float* __restrict__ x, const float* __restrict__ counts,
                              const int* __restrict__ seg, float* __restrict__ anchor,
                              int T, int D, int A) {
    int b = blockIdx.x / A, a = blockIdx.x % A;
    int t0 = seg[a], t1 = seg[a + 1];
    float inv = 1.0f / counts[a];
    int rs = D >> 2;
    const float4* x4 = (const float4*)x + (size_t)b * T * rs;
    float4* an4 = (float4*)anchor + (size_t)blockIdx.x * rs;
    for (int d4 = threadIdx.x; d4 < rs; d4 += blockDim.x) {
        float4 acc = make_float4(0.f, 0.f, 0.f, 0.f);
        const float4* p = x4 + (size_t)t0 * rs + d4;
        int t = t0;
        for (; t + 4 <= t1; t += 4) {
            float4 v0 = p[0];
            float4 v1 = p[(size_t)rs];
            float4 v2 = p[(size_t)2 * rs];
            float4 v3 = p[(size_t)3 * rs];
            acc.x += (v0.x + v1.x) + (v2.x + v3.x);
            acc.y += (v0.y + v1.y) + (v2.y + v3.y);
            acc.z += (v0.z + v1.z) + (v2.z + v3.z);
            acc.w += (v0.w + v1.w) + (v2.w + v3.w);
            p += (size_t)4 * rs;
        }
        for (; t < t1; ++t) {
            float4 v = *p;
            acc.x += v.x; acc.y += v.y; acc.z += v.z; acc.w += v.w;
            p += rs;
        }
        an4[d4] = make_float4(acc.x * inv, acc.y * inv, acc.z * inv, acc.w * inv);
    }
}

// 1 block; computes M = W^h entirely in LDS (A <= 64).
__global__ void mpow_kernel(const float* __restrict__ W, const int* __restrict__ hops,
                            float* __restrict__ M, int A) {
    __shared__ float cur[64 * 64];
    __shared__ float nxt[64 * 64];
    int n = A * A;
    for (int i = threadIdx.x; i < n; i += blockDim.x) cur[i] = W[i];
    int h = hops[0]; if (h < 1) h = 1;
    for (int it = 1; it < h; ++it) {
        __syncthreads();
        for (int i = threadIdx.x; i < n; i += blockDim.x) {
            int r = i / A, c = i % A;
            float s = 0.f;
            for (int k = 0; k < A; ++k) s += W[r * A + k] * cur[k * A + c];
            nxt[i] = s;
        }
        __syncthreads();
        for (int i = threadIdx.x; i < n; i += blockDim.x) cur[i] = nxt[i];
    }
    __syncthreads();
    for (int i = threadIdx.x; i < n; i += blockDim.x) M[i] = cur[i];
}

// grid = B*A blocks; aggb[b,a,:] = bf16( sum_c M[a,c] * anchor[b,c,:] )
__global__ void agg_kernel(const float* __restrict__ anchor, const float* __restrict__ M,
                           short* __restrict__ aggb, int D, int A) {
    int b = blockIdx.x / A, a = blockIdx.x % A;
    __shared__ float row[64];
    if (threadIdx.x < A) row[threadIdx.x] = M[a * A + threadIdx.x];
    __syncthreads();
    int rs = D >> 2;
    const float4* an4 = (const float4*)anchor;
    short4* ag4 = (short4*)aggb;
    for (int d4 = threadIdx.x; d4 < rs; d4 += blockDim.x) {
        float4 acc = make_float4(0.f, 0.f, 0.f, 0.f);
        for (int c = 0; c < A; ++c) {
            float w = row[c];
            float4 v = an4[((size_t)b * A + c) * rs + d4];
            acc.x += w * v.x; acc.y += w * v.y; acc.z += w * v.z; acc.w += w * v.w;
        }
        short4 o;
        o.x = f2bf(acc.x); o.y = f2bf(acc.y); o.z = f2bf(acc.z); o.w = f2bf(acc.w);
        ag4[(size_t)blockIdx.x * rs + d4] = o;
    }
}

// W_proj f32 -> bf16, 8 elements per thread.
__global__ void convW_kernel(const float* __restrict__ W, short* __restrict__ Wb,
                             long long n8) {
    long long i = (long long)blockIdx.x * blockDim.x + threadIdx.x;
    if (i >= n8) return;
    const float4* p = (const float4*)W + i * 2;
    float4 v0 = p[0], v1 = p[1];
    short4* q = (short4*)Wb + i * 2;
    short4 o0, o1;
    o0.x = f2bf(v0.x); o0.y = f2bf(v0.y); o0.z = f2bf(v0.z); o0.w = f2bf(v0.w);
    o1.x = f2bf(v1.x); o1.y = f2bf(v1.y); o1.z = f2bf(v1.z); o1.w = f2bf(v1.w);
    q[0] = o0; q[1] = o1;
}

// Y[r,d] = aggb[r,:] . Wpb[d,:]  via mfma_f32_16x16x32_bf16, operands from L2.
// Block = 4 waves; block tile 16 r x 64 d (wave w owns d-offset w*16).
// A-frag: lane holds Ag[rBase + (lane&15)][k0 + (lane>>4)*8 .. +8)
// B-frag: lane holds Wp[dBase + (lane&15)][k0 + (lane>>4)*8 .. +8)
// D: col = lane&15, row = (lane>>4)*4 + j
__global__ __launch_bounds__(256) void ymfma_kernel(
        const short* __restrict__ Agb, const short* __restrict__ Wpb,
        float* __restrict__ Y, int D) {
    int wave = threadIdx.x >> 6;
    int lane = threadIdx.x & 63;
    int rBase = blockIdx.x * 16;
    int dBase = blockIdx.y * 64 + wave * 16;
    int rc = lane & 15;
    int kOff = (lane >> 4) * 8;
    const short* aPtr = Agb + (size_t)(rBase + rc) * D + kOff;
    const short* bPtr = Wpb + (size_t)(dBase + rc) * D + kOff;
    f32x4 acc = {0.f, 0.f, 0.f, 0.f};
    #pragma unroll 8
    for (int k = 0; k < D; k += 32) {
        bf16x8 af = *(const bf16x8*)(aPtr + k);
        bf16x8 bf = *(const bf16x8*)(bPtr + k);
        acc = __builtin_amdgcn_mfma_f32_16x16x32_bf16(af, bf, acc, 0, 0, 0);
    }
    int orow = (lane >> 4) * 4;
    #pragma unroll
    for (int j = 0; j < 4; ++j)
        Y[(size_t)(rBase + orow + j) * D + dBase + rc] = acc[j];
}

// grid = B*T/OROWS blocks, 256 threads; out row = x row + tg * Y[gathered row]
#define OROWS 4
__global__ void out_kernel(const float* __restrict__ x, const float* __restrict__ Y,
                           const int* __restrict__ assign, const float* __restrict__ gate,
                           float* __restrict__ out, int T, int D, int A) {
    float tg = tanhf(gate[0]);
    int rs = D >> 2;
    int bt0 = blockIdx.x * OROWS;
    const float4* x4 = (const float4*)x;
    const float4* y4 = (const float4*)Y;
    float4* o4 = (float4*)out;
    #pragma unroll
    for (int r = 0; r < OROWS; ++r) {
        int bt = bt0 + r;
        int b = bt / T;
        int t = bt - b * T;
        int a = assign[t];
        const float4* yr = y4 + ((size_t)b * A + a) * rs;
        for (int d4 = threadIdx.x; d4 < rs; d4 += blockDim.x) {
            float4 xv = x4[(size_t)bt * rs + d4];
            float4 yv = yr[d4];
            o4[(size_t)bt * rs + d4] = make_float4(xv.x + tg * yv.x, xv.y + tg * yv.y,
                                                   xv.z + tg * yv.z, xv.w + tg * yv.w);
        }
    }
}

extern "C" void kernel_launch(void* const* d_in, const int* in_sizes, int n_in,
                              void* d_out, int out_size, void* d_ws, size_t ws_size,
                              hipStream_t stream) {
    const float* x      = (const float*)d_in[0];
    const float* Wp     = (const float*)d_in[1];
    const float* gate   = (const float*)d_in[2];
    const int*   assign = (const int*)d_in[3];
    const float* Wg     = (const float*)d_in[4];
    const float* counts = (const float*)d_in[5];
    const int*   hops   = (const int*)d_in[6];
    float* out = (float*)d_out;

    int T = in_sizes[3];
    int A = in_sizes[5];
    int D = (int)(sqrt((double)in_sizes[1]) + 0.5);
    int B = (int)(in_sizes[0] / ((long long)T * D));
    int R = B * A;

    // workspace layout (16B-aligned chunks)
    float* anchor = (float*)d_ws;                       // R*D f32
    float* Y      = anchor + (size_t)R * D;             // R*D f32
    float* M      = Y + (size_t)R * D;                  // A*A f32
    short* Agb    = (short*)(M + (size_t)A * A);        // R*D bf16
    short* Wpb    = Agb + (size_t)R * D;                // D*D bf16
    int*   seg    = (int*)(Wpb + (size_t)D * D);        // A+1 ints

    seg_kernel<<<1, 128, 0, stream>>>(assign, T, A, seg);
    anchor_kernel<<<R, 256, 0, stream>>>(x, counts, seg, anchor, T, D, A);
    mpow_kernel<<<1, 256, 0, stream>>>(Wg, hops, M, A);
    agg_kernel<<<R, 256, 0, stream>>>(anchor, M, Agb, D, A);
    long long n8 = (long long)D * D / 8;
    convW_kernel<<<(int)((n8 + 255) / 256), 256, 0, stream>>>(Wp, Wpb, n8);
    dim3 g(R / 16, D / 64);
    ymfma_kernel<<<g, 256, 0, stream>>>(Agb, Wpb, Y, D);
    out_kernel<<<B * T / OROWS, 256, 0, stream>>>(x, Y, assign, gate, out, T, D, A);
}

// Round 4
// 64.392 us; speedup vs baseline: 3.4472x; 1.1055x over previous
//
#include <hip/hip_runtime.h>
#include <cmath>

// Pipeline:
//  prep:  seg[a] = lower_bound(assign,a);  M = W_graph^hops;  Wpb = bf16(W_proj)
//  anchor[b,a,:] = sum_{t in seg} x[b,t,:] / counts[a]    (f32)
//  aggb[b,a,:]   = bf16( sum_c M[a,c] * anchor[b,c,:] )
//  Y[r,d]        = mfma bf16 GEMM: aggb[r,:] . Wpb[d,:]   (f32 out, no LDS)
//  out[b,t,:]    = x[b,t,:] + tanh(gate) * Y[b,assign[t],:]

typedef __attribute__((ext_vector_type(8))) short bf16x8;
typedef __attribute__((ext_vector_type(4))) float f32x4;

__device__ inline short f2bf(float f) {            // round-to-nearest-even
    unsigned u = __float_as_uint(f);
    unsigned r = (u + 0x7FFFu + ((u >> 16) & 1u)) >> 16;
    return (short)r;
}

// block 0: seg (binary search); block 1: M = W^h; blocks 2+: W_proj -> bf16
__global__ void prep_kernel(const int* __restrict__ assign, int T, int A,
                            int* __restrict__ seg,
                            const float* __restrict__ Wg, const int* __restrict__ hops,
                            float* __restrict__ M,
                            const float* __restrict__ Wp, short* __restrict__ Wpb,
                            long long n8) {
    __shared__ float cur[64 * 64];
    __shared__ float nxt[64 * 64];
    if (blockIdx.x == 0) {
        int a = threadIdx.x;
        if (a <= A) {
            int lo = 0, hi = T;
            while (lo < hi) { int mid = (lo + hi) >> 1; if (assign[mid] < a) lo = mid + 1; else hi = mid; }
            seg[a] = lo;
        }
    } else if (blockIdx.x == 1) {
        int n = A * A;
        for (int i = threadIdx.x; i < n; i += blockDim.x) cur[i] = Wg[i];
        int h = hops[0]; if (h < 1) h = 1;
        for (int it = 1; it < h; ++it) {
            __syncthreads();
            for (int i = threadIdx.x; i < n; i += blockDim.x) {
                int r = i / A, c = i % A;
                float s = 0.f;
                for (int k = 0; k < A; ++k) s += Wg[r * A + k] * cur[k * A + c];
                nxt[i] = s;
            }
            __syncthreads();
            for (int i = threadIdx.x; i < n; i += blockDim.x) cur[i] = nxt[i];
        }
        __syncthreads();
        for (int i = threadIdx.x; i < n; i += blockDim.x) M[i] = cur[i];
    } else {
        long long i = (long long)(blockIdx.x - 2) * blockDim.x + threadIdx.x;
        if (i < n8) {
            const float4* p = (const float4*)Wp + i * 2;
            float4 v0 = p[0], v1 = p[1];
            short4* q = (short4*)Wpb + i * 2;
            short4 o0, o1;
            o0.x = f2bf(v0.x); o0.y = f2bf(v0.y); o0.z = f2bf(v0.z); o0.w = f2bf(v0.w);
            o1.x = f2bf(v1.x); o1.y = f2bf(v1.y); o1.z = f2bf(v1.z); o1.w = f2bf(v1.w);
            q[0] = o0; q[1] = o1;
        }
    }
}

// grid = B*A blocks, 256 threads; block reduces one (b,a) segment.
// t-loop unrolled x8: 8 outstanding HBM loads per lane.
__global__ void anchor_kernel(const float* __restrict__ x, const float* __restrict__ counts,
                              const int* __restrict__ seg, float* __restrict__ anchor,
                              int T, int D, int A) {
    int b = blockIdx.x / A, a = blockIdx.x % A;
    int t0 = seg[a], t1 = seg[a + 1];
    float inv = 1.0f / counts[a];
    int rs = D >> 2;
    const float4* x4 = (const float4*)x + (size_t)b * T * rs;
    float4* an4 = (float4*)anchor + (size_t)blockIdx.x * rs;
    for (int d4 = threadIdx.x; d4 < rs; d4 += blockDim.x) {
        float4 acc = make_float4(0.f, 0.f, 0.f, 0.f);
        const float4* p = x4 + (size_t)t0 * rs + d4;
        int t = t0;
        for (; t + 8 <= t1; t += 8) {
            float4 v0 = p[0];
            float4 v1 = p[(size_t)rs];
            float4 v2 = p[(size_t)2 * rs];
            float4 v3 = p[(size_t)3 * rs];
            float4 v4 = p[(size_t)4 * rs];
            float4 v5 = p[(size_t)5 * rs];
            float4 v6 = p[(size_t)6 * rs];
            float4 v7 = p[(size_t)7 * rs];
            acc.x += ((v0.x + v1.x) + (v2.x + v3.x)) + ((v4.x + v5.x) + (v6.x + v7.x));
            acc.y += ((v0.y + v1.y) + (v2.y + v3.y)) + ((v4.y + v5.y) + (v6.y + v7.y));
            acc.z += ((v0.z + v1.z) + (v2.z + v3.z)) + ((v4.z + v5.z) + (v6.z + v7.z));
            acc.w += ((v0.w + v1.w) + (v2.w + v3.w)) + ((v4.w + v5.w) + (v6.w + v7.w));
            p += (size_t)8 * rs;
        }
        for (; t < t1; ++t) {
            float4 v = *p;
            acc.x += v.x; acc.y += v.y; acc.z += v.z; acc.w += v.w;
            p += rs;
        }
        an4[d4] = make_float4(acc.x * inv, acc.y * inv, acc.z * inv, acc.w * inv);
    }
}

// grid = B*A blocks; aggb[b,a,:] = bf16( sum_c M[a,c] * anchor[b,c,:] )
__global__ void agg_kernel(const float* __restrict__ anchor, const float* __restrict__ M,
                           short* __restrict__ aggb, int D, int A) {
    int b = blockIdx.x / A, a = blockIdx.x % A;
    __shared__ float row[64];
    if (threadIdx.x < A) row[threadIdx.x] = M[a * A + threadIdx.x];
    __syncthreads();
    int rs = D >> 2;
    const float4* an4 = (const float4*)anchor;
    short4* ag4 = (short4*)aggb;
    for (int d4 = threadIdx.x; d4 < rs; d4 += blockDim.x) {
        float4 acc = make_float4(0.f, 0.f, 0.f, 0.f);
        for (int c = 0; c < A; ++c) {
            float w = row[c];
            float4 v = an4[((size_t)b * A + c) * rs + d4];
            acc.x += w * v.x; acc.y += w * v.y; acc.z += w * v.z; acc.w += w * v.w;
        }
        short4 o;
        o.x = f2bf(acc.x); o.y = f2bf(acc.y); o.z = f2bf(acc.z); o.w = f2bf(acc.w);
        ag4[(size_t)blockIdx.x * rs + d4] = o;
    }
}

// Y[r,d] = aggb[r,:] . Wpb[d,:]  via mfma_f32_16x16x32_bf16, operands from L2.
// Block = 4 waves; block tile 16 r x 64 d (wave w owns d-offset w*16).
__global__ __launch_bounds__(256) void ymfma_kernel(
        const short* __restrict__ Agb, const short* __restrict__ Wpb,
        float* __restrict__ Y, int D) {
    int wave = threadIdx.x >> 6;
    int lane = threadIdx.x & 63;
    int rBase = blockIdx.x * 16;
    int dBase = blockIdx.y * 64 + wave * 16;
    int rc = lane & 15;
    int kOff = (lane >> 4) * 8;
    const short* aPtr = Agb + (size_t)(rBase + rc) * D + kOff;
    const short* bPtr = Wpb + (size_t)(dBase + rc) * D + kOff;
    f32x4 acc = {0.f, 0.f, 0.f, 0.f};
    #pragma unroll 8
    for (int k = 0; k < D; k += 32) {
        bf16x8 af = *(const bf16x8*)(aPtr + k);
        bf16x8 bf = *(const bf16x8*)(bPtr + k);
        acc = __builtin_amdgcn_mfma_f32_16x16x32_bf16(af, bf, acc, 0, 0, 0);
    }
    int orow = (lane >> 4) * 4;
    #pragma unroll
    for (int j = 0; j < 4; ++j)
        Y[(size_t)(rBase + orow + j) * D + dBase + rc] = acc[j];
}

// grid = B*T/OROWS blocks, 256 threads; out row = x row + tg * Y[gathered row]
#define OROWS 8
__global__ void out_kernel(const float* __restrict__ x, const float* __restrict__ Y,
                           const int* __restrict__ assign, const float* __restrict__ gate,
                           float* __restrict__ out, int T, int D, int A) {
    float tg = tanhf(gate[0]);
    int rs = D >> 2;
    int bt0 = blockIdx.x * OROWS;
    const float4* x4 = (const float4*)x;
    const float4* y4 = (const float4*)Y;
    float4* o4 = (float4*)out;
    #pragma unroll
    for (int r = 0; r < OROWS; ++r) {
        int bt = bt0 + r;
        int b = bt / T;
        int t = bt - b * T;
        int a = assign[t];
        const float4* yr = y4 + ((size_t)b * A + a) * rs;
        for (int d4 = threadIdx.x; d4 < rs; d4 += blockDim.x) {
            float4 xv = x4[(size_t)bt * rs + d4];
            float4 yv = yr[d4];
            o4[(size_t)bt * rs + d4] = make_float4(xv.x + tg * yv.x, xv.y + tg * yv.y,
                                                   xv.z + tg * yv.z, xv.w + tg * yv.w);
        }
    }
}

extern "C" void kernel_launch(void* const* d_in, const int* in_sizes, int n_in,
                              void* d_out, int out_size, void* d_ws, size_t ws_size,
                              hipStream_t stream) {
    const float* x      = (const float*)d_in[0];
    const float* Wp     = (const float*)d_in[1];
    const float* gate   = (const float*)d_in[2];
    const int*   assign = (const int*)d_in[3];
    const float* Wg     = (const float*)d_in[4];
    const float* counts = (const float*)d_in[5];
    const int*   hops   = (const int*)d_in[6];
    float* out = (float*)d_out;

    int T = in_sizes[3];
    int A = in_sizes[5];
    int D = (int)(sqrt((double)in_sizes[1]) + 0.5);
    int B = (int)(in_sizes[0] / ((long long)T * D));
    int R = B * A;

    // workspace layout (16B-aligned chunks)
    float* anchor = (float*)d_ws;                       // R*D f32
    float* Y      = anchor + (size_t)R * D;             // R*D f32
    float* M      = Y + (size_t)R * D;                  // A*A f32
    short* Agb    = (short*)(M + (size_t)A * A);        // R*D bf16
    short* Wpb    = Agb + (size_t)R * D;                // D*D bf16
    int*   seg    = (int*)(Wpb + (size_t)D * D);        // A+1 ints

    long long n8 = (long long)D * D / 8;
    int prepBlocks = 2 + (int)((n8 + 255) / 256);
    prep_kernel<<<prepBlocks, 256, 0, stream>>>(assign, T, A, seg, Wg, hops, M, Wp, Wpb, n8);
    anchor_kernel<<<R, 256, 0, stream>>>(x, counts, seg, anchor, T, D, A);
    agg_kernel<<<R, 256, 0, stream>>>(anchor, M, Agb, D, A);
    dim3 g(R / 16, D / 64);
    ymfma_kernel<<<g, 256, 0, stream>>>(Agb, Wpb, Y, D);
    out_kernel<<<B * T / OROWS, 256, 0, stream>>>(x, Y, assign, gate, out, T, D, A);
}